// Round 8
// baseline (130.525 us; speedup 1.0000x reference)
//
#include <hip/hip_runtime.h>
#include <hip/hip_bf16.h>
#include <stdint.h>

typedef __bf16 bf16;
typedef __bf16 bf16x8 __attribute__((ext_vector_type(8)));
typedef __bf16 bf16x4 __attribute__((ext_vector_type(4)));
typedef float  f32x4  __attribute__((ext_vector_type(4)));
typedef float  f32x16 __attribute__((ext_vector_type(16)));
typedef unsigned int u32;

#define DM 1024
#define NH 16
#define HD 64
#define TT 2048

// log2(e)/8 : puts QK^T scores directly in exp2 domain
#define QSCALE 0.18033688011112042f

__global__ void cvt_all(const float* __restrict__ x,  const float* __restrict__ wq,
                        const float* __restrict__ wk, const float* __restrict__ wv,
                        const float* __restrict__ wo,
                        bf16* __restrict__ xb,  bf16* __restrict__ wqb,
                        bf16* __restrict__ wkb, bf16* __restrict__ wvb,
                        bf16* __restrict__ wob) {
  const int i = (blockIdx.x * blockDim.x + threadIdx.x) * 4;
  const float* src; bf16* dst; int off;
  if (i < 4194304)      { src = x;  dst = xb;  off = i; }
  else {
    const int j = i - 4194304;
    const int w = j >> 20;
    off = j & 1048575;
    src = (w == 0) ? wq : (w == 1) ? wk : (w == 2) ? wv : wo;
    dst = (w == 0) ? wqb : (w == 1) ? wkb : (w == 2) ? wvb : wob;
  }
  const float4 v = *reinterpret_cast<const float4*>(src + off);
  bf16x4 o = { (bf16)v.x, (bf16)v.y, (bf16)v.z, (bf16)v.w };
  *reinterpret_cast<bf16x4*>(dst + off) = o;
}

static __device__ __forceinline__ void gload_lds16(const bf16* g, bf16* l) {
  __builtin_amdgcn_global_load_lds(
      (__attribute__((address_space(1))) void*)g,
      (__attribute__((address_space(3))) void*)l, 16, 0, 0);
}

// XOR swizzle: spreads the 8 16B-slots of a 128B row across banks by row
static __device__ __forceinline__ int swzb(int lin) {
  return lin ^ (((lin >> 7) & 7) << 4);
}

static __device__ __forceinline__ u32 cvtpk(float lo, float hi) {
  u32 r;
  asm("v_cvt_pk_bf16_f32 %0, %1, %2" : "=v"(r) : "v"(lo), "v"(hi));
  return r;
}
static __device__ __forceinline__ void plswap(u32& a, u32& b) {
  // swap high 32 lanes of a with low 32 lanes of b
  asm("v_permlane32_swap_b32 %0, %1" : "+v"(a), "+v"(b));
}

// ---------------- QKV projection (m97-style) ----------------
__launch_bounds__(256, 3)
__global__ void gemm_qkv(const bf16* __restrict__ X, const bf16* __restrict__ Wq,
                         const bf16* __restrict__ Wk, const bf16* __restrict__ Wv,
                         bf16* __restrict__ Qb, bf16* __restrict__ Kb,
                         bf16* __restrict__ Vtb) {
  __shared__ bf16 As[128 * 32];
  __shared__ bf16 Bs[128 * 32];
  const int tid  = threadIdx.x;
  const int lane = tid & 63;
  const int wv   = tid >> 6;
  const int lg   = lane >> 4, lc = lane & 15;
  const int m0   = blockIdx.x * 128;
  const int ng   = blockIdx.y * 128;
  const int which = ng >> 10;                 // 0=Q 1=K 2=V
  const bf16* W = (which == 0) ? Wq : ((which == 1) ? Wk : Wv);
  const int n0 = ng & 1023;
  const int wm = wv >> 1, wn = wv & 1;

  f32x4 acc[4][4] = {};

  for (int k0 = 0; k0 < DM; k0 += 32) {
#pragma unroll
    for (int c = 0; c < 2; ++c) {
      const int e   = wv * 512 + c * 2048 + lane * 8;
      const int row = e >> 5, col = e & 31;
      gload_lds16(X + (size_t)(m0 + row) * DM + k0 + col, &As[wv * 512 + c * 2048]);
      gload_lds16(W + (size_t)(n0 + row) * DM + k0 + col, &Bs[wv * 512 + c * 2048]);
    }
    __syncthreads();
    bf16x8 a[4], b[4];
#pragma unroll
    for (int i = 0; i < 4; ++i)
      a[i] = *reinterpret_cast<const bf16x8*>(&As[(wm * 64 + i * 16 + lc) * 32 + lg * 8]);
#pragma unroll
    for (int j = 0; j < 4; ++j)
      b[j] = *reinterpret_cast<const bf16x8*>(&Bs[(wn * 64 + j * 16 + lc) * 32 + lg * 8]);
#pragma unroll
    for (int i = 0; i < 4; ++i)
#pragma unroll
      for (int j = 0; j < 4; ++j)
        acc[i][j] = __builtin_amdgcn_mfma_f32_16x16x32_bf16(a[i], b[j], acc[i][j], 0, 0, 0);
    __syncthreads();
  }

#pragma unroll
  for (int i = 0; i < 4; ++i) {
    const int mg = m0 + wm * 64 + i * 16 + lg * 4;
    const int bb = mg >> 11, t = mg & 2047;
#pragma unroll
    for (int j = 0; j < 4; ++j) {
      const int nl = n0 + wn * 64 + j * 16 + lc;
      const int h = nl >> 6, d = nl & 63;
      const int bh = bb * NH + h;
      const f32x4 v = acc[i][j];
      if (which == 0) {
        bf16* p = Qb + ((size_t)bh * TT + t) * HD + d;
#pragma unroll
        for (int r = 0; r < 4; ++r) p[r * HD] = (bf16)(v[r] * QSCALE);
      } else if (which == 1) {
        bf16* p = Kb + ((size_t)bh * TT + t) * HD + d;
#pragma unroll
        for (int r = 0; r < 4; ++r) p[r * HD] = (bf16)v[r];
      } else {
        bf16x4 pk = { (bf16)v[0], (bf16)v[1], (bf16)v[2], (bf16)v[3] };
        *reinterpret_cast<bf16x4*>(Vtb + ((size_t)bh * HD + d) * TT + t) = pk;
      }
    }
  }
}

// ---------------- flash attention: 32x32 MFMA, in-register P ----------------
// 1024 blocks x 2 waves x 32 q-rows. Blocks pop 64-row chunks (bh, qc) from an
// atomic work queue, heavy-first (qc = 31 - idx>>5) -> balance independent of
// dispatch mapping. Swapped QK^T (32x32x16): lane's col q = lane&31 is fixed,
// so softmax is in-lane tree + ONE shfl_xor(32). P re-fragmented for PV
// entirely in registers via v_cvt_pk_bf16_f32 + v_permlane32_swap_b32 (T12).
// Counted-vmcnt double-buffered K/V^T staging, XOR-swizzled. T13 defer-max.
#define NCHUNK 1024
#define MF32(a, b, c) __builtin_amdgcn_mfma_f32_32x32x16_bf16((a), (b), (c), 0, 0, 0)

__launch_bounds__(128, 2)
__global__ void attn_fwd(const bf16* __restrict__ Qb, const bf16* __restrict__ Kb,
                         const bf16* __restrict__ Vtb, bf16* __restrict__ Yb,
                         u32* __restrict__ ctr) {
  __shared__ bf16 Ks[2][4096];     // [buf][64 kv x 64 d] swizzled rows
  __shared__ bf16 Vs[2][4096];     // [buf][64 d x 64 kv] swizzled rows
  __shared__ int sIdx;

  const int tid  = threadIdx.x;
  const int lane = tid & 63;
  const int wv   = tid >> 6;         // 0..1
  const int m31  = lane & 31;
  const int hi   = lane >> 5;
  const int hi16 = hi << 4;
  const int hi4  = hi << 2;
  const int xr   = (m31 & 7) << 4;   // row-based XOR for 16B slots
  const int kRow = m31 * 128;        // byte row base within a 32-row subtile
  int colx[4];
#pragma unroll
  for (int i = 0; i < 4; ++i) colx[i] = (i * 32 + hi16) ^ xr;

  // staging offsets: dest linear (wave-uniform base + lane*16), src pre-swizzled
  int dstb[4], koff[4], voff[4];
#pragma unroll
  for (int c = 0; c < 4; ++c) {
    const int base = (wv * 4 + c) * 1024;
    const int lin  = base + lane * 16;
    dstb[c] = base;
    koff[c] = swzb(lin);
    voff[c] = (lin >> 7) * (TT * 2) + (swzb(lin) & 127);
  }

  for (;;) {
    if (tid == 0) sIdx = (int)atomicAdd(ctr, 1u);
    __syncthreads();                 // publish sIdx; fences LDS buffer reuse
    const int idx = sIdx;
    if (idx >= NCHUNK) break;

    const int qc  = 31 - (idx >> 5); // heavy chunks first
    const int bh  = idx & 31;
    const int NT  = qc + 1;
    const int qb0 = qc * 64 + wv * 32;
    const int qrow = qb0 + m31;

    const bf16* Qg = Qb  + (size_t)bh * TT * HD;
    const bf16* Kg = Kb  + (size_t)bh * TT * HD;
    const bf16* Vg = Vtb + (size_t)bh * HD * TT;

    // Q fragments (B-operand): B[k=d][n=q], lane holds q=m31, d = ds*16+8*hi+j
    bf16x8 qr0 = *reinterpret_cast<const bf16x8*>(Qg + (size_t)qrow * HD + 0  + hi * 8);
    bf16x8 qr1 = *reinterpret_cast<const bf16x8*>(Qg + (size_t)qrow * HD + 16 + hi * 8);
    bf16x8 qr2 = *reinterpret_cast<const bf16x8*>(Qg + (size_t)qrow * HD + 32 + hi * 8);
    bf16x8 qr3 = *reinterpret_cast<const bf16x8*>(Qg + (size_t)qrow * HD + 48 + hi * 8);

    f32x16 o0 = {}, o1 = {};         // O^T rows d = dsub*32 + crow, col q = m31
    float m_run = -INFINITY, l_run = 0.f;

#define STAGE(buf, kv)                                                          \
    {                                                                           \
      _Pragma("unroll")                                                         \
      for (int c = 0; c < 4; ++c) {                                             \
        gload_lds16((const bf16*)((const char*)Kg + (size_t)(kv) * 8192 + koff[c]), \
                    (bf16*)((char*)Ks[buf] + dstb[c]));                         \
        gload_lds16((const bf16*)((const char*)Vg + (size_t)(kv) * 128 + voff[c]),  \
                    (bf16*)((char*)Vs[buf] + dstb[c]));                         \
      }                                                                         \
    }

    STAGE(0, 0);                     // 8 loads outstanding
    int cur = 0;
    for (int ti = 0; ti < NT; ++ti) {
      if (ti + 1 < NT) {
        STAGE(cur ^ 1, ti + 1);
        asm volatile("s_waitcnt vmcnt(8)" ::: "memory");
      } else {
        asm volatile("s_waitcnt vmcnt(0)" ::: "memory");
      }
      __builtin_amdgcn_s_barrier();
      __builtin_amdgcn_sched_barrier(0);

      const char* ksb = (const char*)Ks[cur];
      const char* vsb = (const char*)Vs[cur];
      const int k0 = ti * 64;
      const bool live = (k0 <= qb0 + 31);   // wave-uniform

      if (live) {
        // ---- QK^T: S^T[kv][q], A = K (m=kv), B = Q (n=q) ----
        f32x16 s0 = {}, s1 = {};
        __builtin_amdgcn_s_setprio(1);
        {
          bf16x8 kf;
          kf = *reinterpret_cast<const bf16x8*>(ksb + kRow + colx[0]); s0 = MF32(kf, qr0, s0);
          kf = *reinterpret_cast<const bf16x8*>(ksb + kRow + colx[1]); s0 = MF32(kf, qr1, s0);
          kf = *reinterpret_cast<const bf16x8*>(ksb + kRow + colx[2]); s0 = MF32(kf, qr2, s0);
          kf = *reinterpret_cast<const bf16x8*>(ksb + kRow + colx[3]); s0 = MF32(kf, qr3, s0);
          kf = *reinterpret_cast<const bf16x8*>(ksb + 4096 + kRow + colx[0]); s1 = MF32(kf, qr0, s1);
          kf = *reinterpret_cast<const bf16x8*>(ksb + 4096 + kRow + colx[1]); s1 = MF32(kf, qr1, s1);
          kf = *reinterpret_cast<const bf16x8*>(ksb + 4096 + kRow + colx[2]); s1 = MF32(kf, qr2, s1);
          kf = *reinterpret_cast<const bf16x8*>(ksb + 4096 + kRow + colx[3]); s1 = MF32(kf, qr3, s1);
        }
        __builtin_amdgcn_s_setprio(0);

        // ---- causal mask (diagonal tile only) ----
        if (k0 + 63 > qb0) {
#pragma unroll
          for (int r = 0; r < 16; ++r) {
            const int kvl = (r & 3) + 8 * (r >> 2) + hi4;
            if (k0 + kvl > qrow)      s0[r] = -INFINITY;
            if (k0 + 32 + kvl > qrow) s1[r] = -INFINITY;
          }
        }

        // ---- row max: in-lane tree over 32 + one cross-half exchange ----
        float q0m = fmaxf(fmaxf(s0[0], s0[1]),  fmaxf(s0[2], s0[3]));
        float q1m = fmaxf(fmaxf(s0[4], s0[5]),  fmaxf(s0[6], s0[7]));
        float q2m = fmaxf(fmaxf(s0[8], s0[9]),  fmaxf(s0[10], s0[11]));
        float q3m = fmaxf(fmaxf(s0[12], s0[13]), fmaxf(s0[14], s0[15]));
        float q4m = fmaxf(fmaxf(s1[0], s1[1]),  fmaxf(s1[2], s1[3]));
        float q5m = fmaxf(fmaxf(s1[4], s1[5]),  fmaxf(s1[6], s1[7]));
        float q6m = fmaxf(fmaxf(s1[8], s1[9]),  fmaxf(s1[10], s1[11]));
        float q7m = fmaxf(fmaxf(s1[12], s1[13]), fmaxf(s1[14], s1[15]));
        float pm = fmaxf(fmaxf(fmaxf(q0m, q1m), fmaxf(q2m, q3m)),
                         fmaxf(fmaxf(q4m, q5m), fmaxf(q6m, q7m)));
        pm = fmaxf(pm, __shfl_xor(pm, 32));

        // ---- T13 defer-rescale: only when some lane's max grew by > 8 ----
        const int need = pm > m_run + 8.f;
        if (__any(need)) {
          const float mn = fmaxf(m_run, pm);
          const float al = __builtin_amdgcn_exp2f(m_run - mn);
          m_run = mn; l_run *= al;
#pragma unroll
          for (int r = 0; r < 16; ++r) { o0[r] *= al; o1[r] *= al; }
        }

#pragma unroll
        for (int r = 0; r < 16; ++r) {
          s0[r] = __builtin_amdgcn_exp2f(s0[r] - m_run);
          s1[r] = __builtin_amdgcn_exp2f(s1[r] - m_run);
        }

        // ---- P -> PV B-fragments in registers (cvt_pk + permlane32_swap) ----
        union PU { u32 w[4]; bf16x8 v; } pu0, pu1, pu2, pu3;
        {
          u32 a0 = cvtpk(s0[0],  s0[1]),  a1 = cvtpk(s0[2],  s0[3]);
          u32 b0 = cvtpk(s0[4],  s0[5]),  b1 = cvtpk(s0[6],  s0[7]);
          plswap(a0, b0); plswap(a1, b1);
          pu0.w[0] = a0; pu0.w[1] = a1; pu0.w[2] = b0; pu0.w[3] = b1;
          u32 c0 = cvtpk(s0[8],  s0[9]),  c1 = cvtpk(s0[10], s0[11]);
          u32 d0 = cvtpk(s0[12], s0[13]), d1 = cvtpk(s0[14], s0[15]);
          plswap(c0, d0); plswap(c1, d1);
          pu1.w[0] = c0; pu1.w[1] = c1; pu1.w[2] = d0; pu1.w[3] = d1;
          u32 e0 = cvtpk(s1[0],  s1[1]),  e1 = cvtpk(s1[2],  s1[3]);
          u32 f0 = cvtpk(s1[4],  s1[5]),  f1 = cvtpk(s1[6],  s1[7]);
          plswap(e0, f0); plswap(e1, f1);
          pu2.w[0] = e0; pu2.w[1] = e1; pu2.w[2] = f0; pu2.w[3] = f1;
          u32 g0 = cvtpk(s1[8],  s1[9]),  g1 = cvtpk(s1[10], s1[11]);
          u32 h0 = cvtpk(s1[12], s1[13]), h1 = cvtpk(s1[14], s1[15]);
          plswap(g0, h0); plswap(g1, h1);
          pu3.w[0] = g0; pu3.w[1] = g1; pu3.w[2] = h0; pu3.w[3] = h1;
        }

        // ---- O^T += V^T P : A = V^T (m=d), B = P (n=q) ----
        __builtin_amdgcn_s_setprio(1);
        {
          bf16x8 vf;
          vf = *reinterpret_cast<const bf16x8*>(vsb + kRow + colx[0]);        o0 = MF32(vf, pu0.v, o0);
          vf = *reinterpret_cast<const bf16x8*>(vsb + 4096 + kRow + colx[0]); o1 = MF32(vf, pu0.v, o1);
          vf = *reinterpret_cast<const bf16x8*>(vsb + kRow + colx[1]);        o0 = MF32(vf, pu1.v, o0);
          vf = *reinterpret_cast<const bf16x8*>(vsb + 4096 + kRow + colx[1]); o1 = MF32(vf, pu1.v, o1);
          vf = *reinterpret_cast<const bf16x8*>(vsb + kRow + colx[2]);        o0 = MF32(vf, pu2.v, o0);
          vf = *reinterpret_cast<const bf16x8*>(vsb + 4096 + kRow + colx[2]); o1 = MF32(vf, pu2.v, o1);
          vf = *reinterpret_cast<const bf16x8*>(vsb + kRow + colx[3]);        o0 = MF32(vf, pu3.v, o0);
          vf = *reinterpret_cast<const bf16x8*>(vsb + 4096 + kRow + colx[3]); o1 = MF32(vf, pu3.v, o1);
        }
        __builtin_amdgcn_s_setprio(0);

        // ---- l-sum (off the pre-PV chain) ----
        float u0 = (s0[0] + s0[1]) + (s0[2] + s0[3]);
        float u1 = (s0[4] + s0[5]) + (s0[6] + s0[7]);
        float u2 = (s0[8] + s0[9]) + (s0[10] + s0[11]);
        float u3 = (s0[12] + s0[13]) + (s0[14] + s0[15]);
        float u4 = (s1[0] + s1[1]) + (s1[2] + s1[3]);
        float u5 = (s1[4] + s1[5]) + (s1[6] + s1[7]);
        float u6 = (s1[8] + s1[9]) + (s1[10] + s1[11]);
        float u7 = (s1[12] + s1[13]) + (s1[14] + s1[15]);
        float rsum = ((u0 + u1) + (u2 + u3)) + ((u4 + u5) + (u6 + u7));
        rsum += __shfl_xor(rsum, 32);
        l_run += rsum;
      }

      __builtin_amdgcn_s_barrier();   // all waves done reading buffer `cur`
      cur ^= 1;
    }
#undef STAGE

    // ---- writeback: y[b*T + q][h*64 + d], d = dsub*32 + rq*8 + hi4 + i ----
    {
      const float linv = 1.f / fmaxf(l_run, 1e-9f);
      bf16* yrow = Yb + ((size_t)((bh >> 4) * TT + qrow)) * DM + (bh & 15) * HD;
#pragma unroll
      for (int rq = 0; rq < 4; ++rq) {
        bf16x4 y0 = { (bf16)(o0[rq * 4 + 0] * linv), (bf16)(o0[rq * 4 + 1] * linv),
                      (bf16)(o0[rq * 4 + 2] * linv), (bf16)(o0[rq * 4 + 3] * linv) };
        *reinterpret_cast<bf16x4*>(yrow + rq * 8 + hi4) = y0;
        bf16x4 y1 = { (bf16)(o1[rq * 4 + 0] * linv), (bf16)(o1[rq * 4 + 1] * linv),
                      (bf16)(o1[rq * 4 + 2] * linv), (bf16)(o1[rq * 4 + 3] * linv) };
        *reinterpret_cast<bf16x4*>(yrow + 32 + rq * 8 + hi4) = y1;
      }
    }
  }
}

// ---------------- output projection (64x128 tiles, 512 blocks = 2/CU) -------
__launch_bounds__(256, 2)
__global__ void gemm_out(const bf16* __restrict__ Y, const bf16* __restrict__ Wo,
                         float* __restrict__ Out) {
  __shared__ bf16 As[64 * 32];
  __shared__ bf16 Bs[128 * 32];
  const int tid  = threadIdx.x;
  const int lane = tid & 63;
  const int wv   = tid >> 6;
  const int lg   = lane >> 4, lc = lane & 15;
  const int m0   = blockIdx.x * 64;
  const int n0   = blockIdx.y * 128;
  const int wm = wv >> 1, wn = wv & 1;   // wave tile: 32 rows x 64 cols

  f32x4 acc[2][4] = {};

  for (int k0 = 0; k0 < DM; k0 += 32) {
    {
      const int e   = wv * 512 + lane * 8;
      const int row = e >> 5, col = e & 31;
      gload_lds16(Y + (size_t)(m0 + row) * DM + k0 + col, &As[wv * 512]);
    }
#pragma unroll
    for (int c = 0; c < 2; ++c) {
      const int e   = wv * 1024 + c * 512 + lane * 8;
      const int row = e >> 5, col = e & 31;
      gload_lds16(Wo + (size_t)(n0 + row) * DM + k0 + col, &Bs[wv * 1024 + c * 512]);
    }
    __syncthreads();
    bf16x8 a[2], b[4];
#pragma unroll
    for (int i = 0; i < 2; ++i)
      a[i] = *reinterpret_cast<const bf16x8*>(&As[(wm * 32 + i * 16 + lc) * 32 + lg * 8]);
#pragma unroll
    for (int j = 0; j < 4; ++j)
      b[j] = *reinterpret_cast<const bf16x8*>(&Bs[(wn * 64 + j * 16 + lc) * 32 + lg * 8]);
#pragma unroll
    for (int i = 0; i < 2; ++i)
#pragma unroll
      for (int j = 0; j < 4; ++j)
        acc[i][j] = __builtin_amdgcn_mfma_f32_16x16x32_bf16(a[i], b[j], acc[i][j], 0, 0, 0);
    __syncthreads();
  }

#pragma unroll
  for (int i = 0; i < 2; ++i) {
    const int mg = m0 + wm * 32 + i * 16 + lg * 4;
#pragma unroll
    for (int j = 0; j < 4; ++j) {
      const int n = n0 + wn * 64 + j * 16 + lc;
#pragma unroll
      for (int r = 0; r < 4; ++r)
        Out[(size_t)(mg + r) * DM + n] = acc[i][j][r];
    }
  }
}

extern "C" void kernel_launch(void* const* d_in, const int* in_sizes, int n_in,
                              void* d_out, int out_size, void* d_ws, size_t ws_size,
                              hipStream_t stream) {
  const float* x  = (const float*)d_in[0];
  const float* Wq = (const float*)d_in[1];
  const float* Wk = (const float*)d_in[2];
  const float* Wv = (const float*)d_in[3];
  const float* Wo = (const float*)d_in[4];
  float* out = (float*)d_out;
  char* ws = (char*)d_ws;
  const size_t MB = 1024 * 1024;

  bf16* xb  = (bf16*)(ws + 0);        // 8 MB, reused as yb after QKV GEMM
  bf16* wqb = (bf16*)(ws + 8  * MB);
  bf16* wkb = (bf16*)(ws + 10 * MB);
  bf16* wvb = (bf16*)(ws + 12 * MB);
  bf16* wob = (bf16*)(ws + 14 * MB);
  bf16* Qb  = (bf16*)(ws + 16 * MB);  // [32,2048,64]
  bf16* Kb  = (bf16*)(ws + 24 * MB);
  bf16* Vtb = (bf16*)(ws + 32 * MB);  // [32,64,2048]
  u32*  ctr = (u32*)(ws + 40 * MB);   // attention work-queue counter
  bf16* yb  = xb;

  hipMemsetAsync(ctr, 0, 4, stream);
  cvt_all<<<8192, 256, 0, stream>>>(x, Wq, Wk, Wv, Wo, xb, wqb, wkb, wvb, wob);
  gemm_qkv<<<dim3(32, 24), 256, 0, stream>>>(xb, wqb, wkb, wvb, Qb, Kb, Vtb);
  attn_fwd<<<1024, 128, 0, stream>>>(Qb, Kb, Vtb, yb, ctr);
  gemm_out<<<dim3(64, 8), 256, 0, stream>>>(yb, wob, out);
}

// Round 9
// 113.869 us; speedup vs baseline: 1.1463x; 1.1463x over previous
//
#include <hip/hip_runtime.h>
#include <hip/hip_bf16.h>
#include <stdint.h>

typedef __bf16 bf16;
typedef __bf16 bf16x8 __attribute__((ext_vector_type(8)));
typedef __bf16 bf16x4 __attribute__((ext_vector_type(4)));
typedef float  f32x4  __attribute__((ext_vector_type(4)));
typedef float  f32x16 __attribute__((ext_vector_type(16)));
typedef unsigned int u32;

#define DM 1024
#define NH 16
#define HD 64
#define TT 2048

// log2(e)/8 : puts QK^T scores directly in exp2 domain
#define QSCALE 0.18033688011112042f

__global__ void cvt_all(const float* __restrict__ x,  const float* __restrict__ wq,
                        const float* __restrict__ wk, const float* __restrict__ wv,
                        const float* __restrict__ wo,
                        bf16* __restrict__ xb,  bf16* __restrict__ wqb,
                        bf16* __restrict__ wkb, bf16* __restrict__ wvb,
                        bf16* __restrict__ wob) {
  const int i = (blockIdx.x * blockDim.x + threadIdx.x) * 4;
  const float* src; bf16* dst; int off;
  if (i < 4194304)      { src = x;  dst = xb;  off = i; }
  else {
    const int j = i - 4194304;
    const int w = j >> 20;
    off = j & 1048575;
    src = (w == 0) ? wq : (w == 1) ? wk : (w == 2) ? wv : wo;
    dst = (w == 0) ? wqb : (w == 1) ? wkb : (w == 2) ? wvb : wob;
  }
  const float4 v = *reinterpret_cast<const float4*>(src + off);
  bf16x4 o = { (bf16)v.x, (bf16)v.y, (bf16)v.z, (bf16)v.w };
  *reinterpret_cast<bf16x4*>(dst + off) = o;
}

static __device__ __forceinline__ void gload_lds16(const bf16* g, bf16* l) {
  __builtin_amdgcn_global_load_lds(
      (__attribute__((address_space(1))) void*)g,
      (__attribute__((address_space(3))) void*)l, 16, 0, 0);
}

// XOR swizzle: spreads the 8 16B-slots of a 128B row across banks by row
static __device__ __forceinline__ int swzb(int lin) {
  return lin ^ (((lin >> 7) & 7) << 4);
}

static __device__ __forceinline__ u32 cvtpk(float lo, float hi) {
  u32 r;
  asm("v_cvt_pk_bf16_f32 %0, %1, %2" : "=v"(r) : "v"(lo), "v"(hi));
  return r;
}
static __device__ __forceinline__ void plswap(u32& a, u32& b) {
  asm("v_permlane32_swap_b32 %0, %1" : "+v"(a), "+v"(b));
}

// ---------------- QKV projection (m97-style) ----------------
__launch_bounds__(256, 3)
__global__ void gemm_qkv(const bf16* __restrict__ X, const bf16* __restrict__ Wq,
                         const bf16* __restrict__ Wk, const bf16* __restrict__ Wv,
                         bf16* __restrict__ Qb, bf16* __restrict__ Kb,
                         bf16* __restrict__ Vtb) {
  __shared__ bf16 As[128 * 32];
  __shared__ bf16 Bs[128 * 32];
  const int tid  = threadIdx.x;
  const int lane = tid & 63;
  const int wv   = tid >> 6;
  const int lg   = lane >> 4, lc = lane & 15;
  const int m0   = blockIdx.x * 128;
  const int ng   = blockIdx.y * 128;
  const int which = ng >> 10;                 // 0=Q 1=K 2=V
  const bf16* W = (which == 0) ? Wq : ((which == 1) ? Wk : Wv);
  const int n0 = ng & 1023;
  const int wm = wv >> 1, wn = wv & 1;

  f32x4 acc[4][4] = {};

  for (int k0 = 0; k0 < DM; k0 += 32) {
#pragma unroll
    for (int c = 0; c < 2; ++c) {
      const int e   = wv * 512 + c * 2048 + lane * 8;
      const int row = e >> 5, col = e & 31;
      gload_lds16(X + (size_t)(m0 + row) * DM + k0 + col, &As[wv * 512 + c * 2048]);
      gload_lds16(W + (size_t)(n0 + row) * DM + k0 + col, &Bs[wv * 512 + c * 2048]);
    }
    __syncthreads();
    bf16x8 a[4], b[4];
#pragma unroll
    for (int i = 0; i < 4; ++i)
      a[i] = *reinterpret_cast<const bf16x8*>(&As[(wm * 64 + i * 16 + lc) * 32 + lg * 8]);
#pragma unroll
    for (int j = 0; j < 4; ++j)
      b[j] = *reinterpret_cast<const bf16x8*>(&Bs[(wn * 64 + j * 16 + lc) * 32 + lg * 8]);
#pragma unroll
    for (int i = 0; i < 4; ++i)
#pragma unroll
      for (int j = 0; j < 4; ++j)
        acc[i][j] = __builtin_amdgcn_mfma_f32_16x16x32_bf16(a[i], b[j], acc[i][j], 0, 0, 0);
    __syncthreads();
  }

#pragma unroll
  for (int i = 0; i < 4; ++i) {
    const int mg = m0 + wm * 64 + i * 16 + lg * 4;
    const int bb = mg >> 11, t = mg & 2047;
#pragma unroll
    for (int j = 0; j < 4; ++j) {
      const int nl = n0 + wn * 64 + j * 16 + lc;
      const int h = nl >> 6, d = nl & 63;
      const int bh = bb * NH + h;
      const f32x4 v = acc[i][j];
      if (which == 0) {
        bf16* p = Qb + ((size_t)bh * TT + t) * HD + d;
#pragma unroll
        for (int r = 0; r < 4; ++r) p[r * HD] = (bf16)(v[r] * QSCALE);
      } else if (which == 1) {
        bf16* p = Kb + ((size_t)bh * TT + t) * HD + d;
#pragma unroll
        for (int r = 0; r < 4; ++r) p[r * HD] = (bf16)v[r];
      } else {
        bf16x4 pk = { (bf16)v[0], (bf16)v[1], (bf16)v[2], (bf16)v[3] };
        *reinterpret_cast<bf16x4*>(Vtb + ((size_t)bh * HD + d) * TT + t) = pk;
      }
    }
  }
}

// ---------------- flash attention: 32x32 MFMA, in-register P ----------------
// 1024 blocks x 2 waves x 32 q-rows, STATIC mapping + HW backfill balance:
// 3 blocks/CU (48KB LDS) -> 768 slots < 1024 blocks, heavy-first qc so the
// dispatcher backfills light blocks behind heavy ones. XCD-grouped bh
// (bid%8 -> 4 bh) keeps each XCD's K/V/Q working set (2.5MB) inside its 4MB
// L2. Depth-2 prefetch over 3 LDS buffers with counted vmcnt. Swapped QK^T
// 32x32x16, in-register P via cvt_pk+permlane32_swap (T12), defer-max (T13).
#define MF32(a, b, c) __builtin_amdgcn_mfma_f32_32x32x16_bf16((a), (b), (c), 0, 0, 0)

__launch_bounds__(128, 2)
__global__ void attn_fwd(const bf16* __restrict__ Qb, const bf16* __restrict__ Kb,
                         const bf16* __restrict__ Vtb, bf16* __restrict__ Yb) {
  __shared__ bf16 Ks[3][4096];     // 3 x [64 kv x 64 d] swizzled rows (24 KB)
  __shared__ bf16 Vs[3][4096];     // 3 x [64 d x 64 kv] swizzled rows (24 KB)

  const int tid  = threadIdx.x;
  const int lane = tid & 63;
  const int wv   = tid >> 6;         // 0..1
  const int m31  = lane & 31;
  const int hi   = lane >> 5;
  const int hi16 = hi << 4;
  const int hi4  = hi << 2;
  const int xr   = (m31 & 7) << 4;
  const int kRow = m31 * 128;
  int colx[4];
#pragma unroll
  for (int i = 0; i < 4; ++i) colx[i] = (i * 32 + hi16) ^ xr;

  // static chunk mapping: heavy-first qc, XCD-grouped bh
  const int u    = blockIdx.x & 31;
  const int bh   = ((u & 7) << 2) | (u >> 3);
  const int qc   = 31 - (blockIdx.x >> 5);
  const int NT   = qc + 1;
  const int qb0  = qc * 64 + wv * 32;
  const int qrow = qb0 + m31;

  const bf16* Qg = Qb  + (size_t)bh * TT * HD;
  const bf16* Kg = Kb  + (size_t)bh * TT * HD;
  const bf16* Vg = Vtb + (size_t)bh * HD * TT;

  // staging offsets: dest linear (wave-uniform base + lane*16), src pre-swizzled
  int dstb[4], koff[4], voff[4];
#pragma unroll
  for (int c = 0; c < 4; ++c) {
    const int base = (wv * 4 + c) * 1024;
    const int lin  = base + lane * 16;
    dstb[c] = base;
    koff[c] = swzb(lin);
    voff[c] = (lin >> 7) * (TT * 2) + (swzb(lin) & 127);
  }

  // Q fragments (B-operand): lane holds q=m31, d = ds*16 + 8*hi + j
  bf16x8 qr0 = *reinterpret_cast<const bf16x8*>(Qg + (size_t)qrow * HD + 0  + hi * 8);
  bf16x8 qr1 = *reinterpret_cast<const bf16x8*>(Qg + (size_t)qrow * HD + 16 + hi * 8);
  bf16x8 qr2 = *reinterpret_cast<const bf16x8*>(Qg + (size_t)qrow * HD + 32 + hi * 8);
  bf16x8 qr3 = *reinterpret_cast<const bf16x8*>(Qg + (size_t)qrow * HD + 48 + hi * 8);

  f32x16 o0 = {}, o1 = {};           // O^T rows d = dsub*32 + crow, col q = m31
  float m_run = -INFINITY, l_run = 0.f;

#define STAGE(buf, kv)                                                          \
  {                                                                             \
    _Pragma("unroll")                                                           \
    for (int c = 0; c < 4; ++c) {                                               \
      gload_lds16((const bf16*)((const char*)Kg + (size_t)(kv) * 8192 + koff[c]), \
                  (bf16*)((char*)Ks[buf] + dstb[c]));                           \
      gload_lds16((const bf16*)((const char*)Vg + (size_t)(kv) * 128 + voff[c]),  \
                  (bf16*)((char*)Vs[buf] + dstb[c]));                           \
    }                                                                           \
  }

  STAGE(0, 0);                       // 8 per-wave loads
  if (NT > 1) STAGE(1, 1);           // +8 -> depth 2

  int cur = 0, nx2 = 2;
  for (int ti = 0; ti < NT; ++ti) {
    if (ti + 2 < NT) {
      STAGE(nx2, ti + 2);
      asm volatile("s_waitcnt vmcnt(16)" ::: "memory");   // tile ti landed
    } else if (ti + 1 < NT) {
      asm volatile("s_waitcnt vmcnt(8)" ::: "memory");
    } else {
      asm volatile("s_waitcnt vmcnt(0)" ::: "memory");
    }
    __builtin_amdgcn_s_barrier();
    __builtin_amdgcn_sched_barrier(0);

    const char* ksb = (const char*)Ks[cur];
    const char* vsb = (const char*)Vs[cur];
    const int k0 = ti * 64;

    // ---- QK^T: S^T[kv][q], A = K (m=kv), B = Q (n=q) ----
    f32x16 s0 = {}, s1 = {};
    __builtin_amdgcn_s_setprio(1);
    {
      bf16x8 kf;
      kf = *reinterpret_cast<const bf16x8*>(ksb + kRow + colx[0]); s0 = MF32(kf, qr0, s0);
      kf = *reinterpret_cast<const bf16x8*>(ksb + kRow + colx[1]); s0 = MF32(kf, qr1, s0);
      kf = *reinterpret_cast<const bf16x8*>(ksb + kRow + colx[2]); s0 = MF32(kf, qr2, s0);
      kf = *reinterpret_cast<const bf16x8*>(ksb + kRow + colx[3]); s0 = MF32(kf, qr3, s0);
      kf = *reinterpret_cast<const bf16x8*>(ksb + 4096 + kRow + colx[0]); s1 = MF32(kf, qr0, s1);
      kf = *reinterpret_cast<const bf16x8*>(ksb + 4096 + kRow + colx[1]); s1 = MF32(kf, qr1, s1);
      kf = *reinterpret_cast<const bf16x8*>(ksb + 4096 + kRow + colx[2]); s1 = MF32(kf, qr2, s1);
      kf = *reinterpret_cast<const bf16x8*>(ksb + 4096 + kRow + colx[3]); s1 = MF32(kf, qr3, s1);
    }
    __builtin_amdgcn_s_setprio(0);

    // ---- causal mask (diagonal tile only) ----
    if (k0 + 63 > qb0) {
#pragma unroll
      for (int r = 0; r < 16; ++r) {
        const int kvl = (r & 3) + 8 * (r >> 2) + hi4;
        if (k0 + kvl > qrow)      s0[r] = -INFINITY;
        if (k0 + 32 + kvl > qrow) s1[r] = -INFINITY;
      }
    }

    // ---- row max: in-lane tree + one cross-half exchange ----
    float q0m = fmaxf(fmaxf(s0[0], s0[1]),  fmaxf(s0[2], s0[3]));
    float q1m = fmaxf(fmaxf(s0[4], s0[5]),  fmaxf(s0[6], s0[7]));
    float q2m = fmaxf(fmaxf(s0[8], s0[9]),  fmaxf(s0[10], s0[11]));
    float q3m = fmaxf(fmaxf(s0[12], s0[13]), fmaxf(s0[14], s0[15]));
    float q4m = fmaxf(fmaxf(s1[0], s1[1]),  fmaxf(s1[2], s1[3]));
    float q5m = fmaxf(fmaxf(s1[4], s1[5]),  fmaxf(s1[6], s1[7]));
    float q6m = fmaxf(fmaxf(s1[8], s1[9]),  fmaxf(s1[10], s1[11]));
    float q7m = fmaxf(fmaxf(s1[12], s1[13]), fmaxf(s1[14], s1[15]));
    float pm = fmaxf(fmaxf(fmaxf(q0m, q1m), fmaxf(q2m, q3m)),
                     fmaxf(fmaxf(q4m, q5m), fmaxf(q6m, q7m)));
    pm = fmaxf(pm, __shfl_xor(pm, 32));

    // ---- T13 defer-rescale ----
    const int need = pm > m_run + 8.f;
    if (__any(need)) {
      const float mn = fmaxf(m_run, pm);
      const float al = __builtin_amdgcn_exp2f(m_run - mn);
      m_run = mn; l_run *= al;
#pragma unroll
      for (int r = 0; r < 16; ++r) { o0[r] *= al; o1[r] *= al; }
    }

#pragma unroll
    for (int r = 0; r < 16; ++r) {
      s0[r] = __builtin_amdgcn_exp2f(s0[r] - m_run);
      s1[r] = __builtin_amdgcn_exp2f(s1[r] - m_run);
    }

    // ---- P -> PV B-fragments in registers (cvt_pk + permlane32_swap) ----
    union PU { u32 w[4]; bf16x8 v; } pu0, pu1, pu2, pu3;
    {
      u32 a0 = cvtpk(s0[0],  s0[1]),  a1 = cvtpk(s0[2],  s0[3]);
      u32 b0 = cvtpk(s0[4],  s0[5]),  b1 = cvtpk(s0[6],  s0[7]);
      plswap(a0, b0); plswap(a1, b1);
      pu0.w[0] = a0; pu0.w[1] = a1; pu0.w[2] = b0; pu0.w[3] = b1;
      u32 c0 = cvtpk(s0[8],  s0[9]),  c1 = cvtpk(s0[10], s0[11]);
      u32 d0 = cvtpk(s0[12], s0[13]), d1 = cvtpk(s0[14], s0[15]);
      plswap(c0, d0); plswap(c1, d1);
      pu1.w[0] = c0; pu1.w[1] = c1; pu1.w[2] = d0; pu1.w[3] = d1;
      u32 e0 = cvtpk(s1[0],  s1[1]),  e1 = cvtpk(s1[2],  s1[3]);
      u32 f0 = cvtpk(s1[4],  s1[5]),  f1 = cvtpk(s1[6],  s1[7]);
      plswap(e0, f0); plswap(e1, f1);
      pu2.w[0] = e0; pu2.w[1] = e1; pu2.w[2] = f0; pu2.w[3] = f1;
      u32 g0 = cvtpk(s1[8],  s1[9]),  g1 = cvtpk(s1[10], s1[11]);
      u32 h0 = cvtpk(s1[12], s1[13]), h1 = cvtpk(s1[14], s1[15]);
      plswap(g0, h0); plswap(g1, h1);
      pu3.w[0] = g0; pu3.w[1] = g1; pu3.w[2] = h0; pu3.w[3] = h1;
    }

    // ---- O^T += V^T P : A = V^T (m=d), B = P (n=q) ----
    __builtin_amdgcn_s_setprio(1);
    {
      bf16x8 vf;
      vf = *reinterpret_cast<const bf16x8*>(vsb + kRow + colx[0]);        o0 = MF32(vf, pu0.v, o0);
      vf = *reinterpret_cast<const bf16x8*>(vsb + 4096 + kRow + colx[0]); o1 = MF32(vf, pu0.v, o1);
      vf = *reinterpret_cast<const bf16x8*>(vsb + kRow + colx[1]);        o0 = MF32(vf, pu1.v, o0);
      vf = *reinterpret_cast<const bf16x8*>(vsb + 4096 + kRow + colx[1]); o1 = MF32(vf, pu1.v, o1);
      vf = *reinterpret_cast<const bf16x8*>(vsb + kRow + colx[2]);        o0 = MF32(vf, pu2.v, o0);
      vf = *reinterpret_cast<const bf16x8*>(vsb + 4096 + kRow + colx[2]); o1 = MF32(vf, pu2.v, o1);
      vf = *reinterpret_cast<const bf16x8*>(vsb + kRow + colx[3]);        o0 = MF32(vf, pu3.v, o0);
      vf = *reinterpret_cast<const bf16x8*>(vsb + 4096 + kRow + colx[3]); o1 = MF32(vf, pu3.v, o1);
    }
    __builtin_amdgcn_s_setprio(0);

    // ---- l-sum (off the pre-PV chain) ----
    float u0 = (s0[0] + s0[1]) + (s0[2] + s0[3]);
    float u1 = (s0[4] + s0[5]) + (s0[6] + s0[7]);
    float u2 = (s0[8] + s0[9]) + (s0[10] + s0[11]);
    float u3 = (s0[12] + s0[13]) + (s0[14] + s0[15]);
    float u4 = (s1[0] + s1[1]) + (s1[2] + s1[3]);
    float u5 = (s1[4] + s1[5]) + (s1[6] + s1[7]);
    float u6 = (s1[8] + s1[9]) + (s1[10] + s1[11]);
    float u7 = (s1[12] + s1[13]) + (s1[14] + s1[15]);
    float rsum = ((u0 + u1) + (u2 + u3)) + ((u4 + u5) + (u6 + u7));
    rsum += __shfl_xor(rsum, 32);
    l_run += rsum;

    __builtin_amdgcn_s_barrier();    // all waves done reading buffer `cur`
    cur = (cur == 2) ? 0 : cur + 1;
    nx2 = (nx2 == 2) ? 0 : nx2 + 1;
  }
#undef STAGE

  // ---- writeback: y[b*T + q][h*64 + d] ----
  {
    const float linv = 1.f / fmaxf(l_run, 1e-9f);
    bf16* yrow = Yb + ((size_t)((bh >> 4) * TT + qrow)) * DM + (bh & 15) * HD;
#pragma unroll
    for (int rq = 0; rq < 4; ++rq) {
      bf16x4 y0 = { (bf16)(o0[rq * 4 + 0] * linv), (bf16)(o0[rq * 4 + 1] * linv),
                    (bf16)(o0[rq * 4 + 2] * linv), (bf16)(o0[rq * 4 + 3] * linv) };
      *reinterpret_cast<bf16x4*>(yrow + rq * 8 + hi4) = y0;
      bf16x4 y1 = { (bf16)(o1[rq * 4 + 0] * linv), (bf16)(o1[rq * 4 + 1] * linv),
                    (bf16)(o1[rq * 4 + 2] * linv), (bf16)(o1[rq * 4 + 3] * linv) };
      *reinterpret_cast<bf16x4*>(yrow + 32 + rq * 8 + hi4) = y1;
    }
  }
}

// ---------------- output projection (64x128 tiles, 512 blocks = 2/CU) -------
__launch_bounds__(256, 2)
__global__ void gemm_out(const bf16* __restrict__ Y, const bf16* __restrict__ Wo,
                         float* __restrict__ Out) {
  __shared__ bf16 As[64 * 32];
  __shared__ bf16 Bs[128 * 32];
  const int tid  = threadIdx.x;
  const int lane = tid & 63;
  const int wv   = tid >> 6;
  const int lg   = lane >> 4, lc = lane & 15;
  const int m0   = blockIdx.x * 64;
  const int n0   = blockIdx.y * 128;
  const int wm = wv >> 1, wn = wv & 1;   // wave tile: 32 rows x 64 cols

  f32x4 acc[2][4] = {};

  for (int k0 = 0; k0 < DM; k0 += 32) {
    {
      const int e   = wv * 512 + lane * 8;
      const int row = e >> 5, col = e & 31;
      gload_lds16(Y + (size_t)(m0 + row) * DM + k0 + col, &As[wv * 512]);
    }
#pragma unroll
    for (int c = 0; c < 2; ++c) {
      const int e   = wv * 1024 + c * 512 + lane * 8;
      const int row = e >> 5, col = e & 31;
      gload_lds16(Wo + (size_t)(n0 + row) * DM + k0 + col, &Bs[wv * 1024 + c * 512]);
    }
    __syncthreads();
    bf16x8 a[2], b[4];
#pragma unroll
    for (int i = 0; i < 2; ++i)
      a[i] = *reinterpret_cast<const bf16x8*>(&As[(wm * 32 + i * 16 + lc) * 32 + lg * 8]);
#pragma unroll
    for (int j = 0; j < 4; ++j)
      b[j] = *reinterpret_cast<const bf16x8*>(&Bs[(wn * 64 + j * 16 + lc) * 32 + lg * 8]);
#pragma unroll
    for (int i = 0; i < 2; ++i)
#pragma unroll
      for (int j = 0; j < 4; ++j)
        acc[i][j] = __builtin_amdgcn_mfma_f32_16x16x32_bf16(a[i], b[j], acc[i][j], 0, 0, 0);
    __syncthreads();
  }

#pragma unroll
  for (int i = 0; i < 2; ++i) {
    const int mg = m0 + wm * 32 + i * 16 + lg * 4;
#pragma unroll
    for (int j = 0; j < 4; ++j) {
      const int n = n0 + wn * 64 + j * 16 + lc;
#pragma unroll
      for (int r = 0; r < 4; ++r)
        Out[(size_t)(mg + r) * DM + n] = acc[i][j][r];
    }
  }
}

extern "C" void kernel_launch(void* const* d_in, const int* in_sizes, int n_in,
                              void* d_out, int out_size, void* d_ws, size_t ws_size,
                              hipStream_t stream) {
  const float* x  = (const float*)d_in[0];
  const float* Wq = (const float*)d_in[1];
  const float* Wk = (const float*)d_in[2];
  const float* Wv = (const float*)d_in[3];
  const float* Wo = (const float*)d_in[4];
  float* out = (float*)d_out;
  char* ws = (char*)d_ws;
  const size_t MB = 1024 * 1024;

  bf16* xb  = (bf16*)(ws + 0);        // 8 MB, reused as yb after QKV GEMM
  bf16* wqb = (bf16*)(ws + 8  * MB);
  bf16* wkb = (bf16*)(ws + 10 * MB);
  bf16* wvb = (bf16*)(ws + 12 * MB);
  bf16* wob = (bf16*)(ws + 14 * MB);
  bf16* Qb  = (bf16*)(ws + 16 * MB);  // [32,2048,64]
  bf16* Kb  = (bf16*)(ws + 24 * MB);
  bf16* Vtb = (bf16*)(ws + 32 * MB);  // [32,64,2048]
  bf16* yb  = xb;

  cvt_all<<<8192, 256, 0, stream>>>(x, Wq, Wk, Wv, Wo, xb, wqb, wkb, wvb, wob);
  gemm_qkv<<<dim3(32, 24), 256, 0, stream>>>(xb, wqb, wkb, wvb, Qb, Kb, Vtb);
  attn_fwd<<<1024, 128, 0, stream>>>(Qb, Kb, Vtb, yb);
  gemm_out<<<dim3(64, 8), 256, 0, stream>>>(yb, wob, out);
}

// Round 10
// 113.795 us; speedup vs baseline: 1.1470x; 1.0007x over previous
//
#include <hip/hip_runtime.h>
#include <hip/hip_bf16.h>
#include <stdint.h>

typedef __bf16 bf16;
typedef __bf16 bf16x8 __attribute__((ext_vector_type(8)));
typedef __bf16 bf16x4 __attribute__((ext_vector_type(4)));
typedef float  f32x4  __attribute__((ext_vector_type(4)));
typedef float  f32x16 __attribute__((ext_vector_type(16)));
typedef unsigned int u32;

#define DM 1024
#define NH 16
#define HD 64
#define TT 2048

// log2(e)/8 : puts QK^T scores directly in exp2 domain
#define QSCALE 0.18033688011112042f

__global__ void cvt_all(const float* __restrict__ x,  const float* __restrict__ wq,
                        const float* __restrict__ wk, const float* __restrict__ wv,
                        const float* __restrict__ wo,
                        bf16* __restrict__ xb,  bf16* __restrict__ wqb,
                        bf16* __restrict__ wkb, bf16* __restrict__ wvb,
                        bf16* __restrict__ wob) {
  const int i = (blockIdx.x * blockDim.x + threadIdx.x) * 4;
  const float* src; bf16* dst; int off;
  if (i < 4194304)      { src = x;  dst = xb;  off = i; }
  else {
    const int j = i - 4194304;
    const int w = j >> 20;
    off = j & 1048575;
    src = (w == 0) ? wq : (w == 1) ? wk : (w == 2) ? wv : wo;
    dst = (w == 0) ? wqb : (w == 1) ? wkb : (w == 2) ? wvb : wob;
  }
  const float4 v = *reinterpret_cast<const float4*>(src + off);
  bf16x4 o = { (bf16)v.x, (bf16)v.y, (bf16)v.z, (bf16)v.w };
  *reinterpret_cast<bf16x4*>(dst + off) = o;
}

static __device__ __forceinline__ void gload_lds16(const bf16* g, bf16* l) {
  __builtin_amdgcn_global_load_lds(
      (__attribute__((address_space(1))) void*)g,
      (__attribute__((address_space(3))) void*)l, 16, 0, 0);
}

// XOR swizzle: spreads the 8 16B-slots of a 128B row across banks by row
static __device__ __forceinline__ int swzb(int lin) {
  return lin ^ (((lin >> 7) & 7) << 4);
}

static __device__ __forceinline__ u32 cvtpk(float lo, float hi) {
  u32 r;
  asm("v_cvt_pk_bf16_f32 %0, %1, %2" : "=v"(r) : "v"(lo), "v"(hi));
  return r;
}
static __device__ __forceinline__ void plswap(u32& a, u32& b) {
  asm("v_permlane32_swap_b32 %0, %1" : "+v"(a), "+v"(b));
}

// ---------------- QKV projection (m97-style) ----------------
__launch_bounds__(256, 3)
__global__ void gemm_qkv(const bf16* __restrict__ X, const bf16* __restrict__ Wq,
                         const bf16* __restrict__ Wk, const bf16* __restrict__ Wv,
                         bf16* __restrict__ Qb, bf16* __restrict__ Kb,
                         bf16* __restrict__ Vtb) {
  __shared__ bf16 As[128 * 32];
  __shared__ bf16 Bs[128 * 32];
  const int tid  = threadIdx.x;
  const int lane = tid & 63;
  const int wv   = tid >> 6;
  const int lg   = lane >> 4, lc = lane & 15;
  const int m0   = blockIdx.x * 128;
  const int ng   = blockIdx.y * 128;
  const int which = ng >> 10;                 // 0=Q 1=K 2=V
  const bf16* W = (which == 0) ? Wq : ((which == 1) ? Wk : Wv);
  const int n0 = ng & 1023;
  const int wm = wv >> 1, wn = wv & 1;

  f32x4 acc[4][4] = {};

  for (int k0 = 0; k0 < DM; k0 += 32) {
#pragma unroll
    for (int c = 0; c < 2; ++c) {
      const int e   = wv * 512 + c * 2048 + lane * 8;
      const int row = e >> 5, col = e & 31;
      gload_lds16(X + (size_t)(m0 + row) * DM + k0 + col, &As[wv * 512 + c * 2048]);
      gload_lds16(W + (size_t)(n0 + row) * DM + k0 + col, &Bs[wv * 512 + c * 2048]);
    }
    __syncthreads();
    bf16x8 a[4], b[4];
#pragma unroll
    for (int i = 0; i < 4; ++i)
      a[i] = *reinterpret_cast<const bf16x8*>(&As[(wm * 64 + i * 16 + lc) * 32 + lg * 8]);
#pragma unroll
    for (int j = 0; j < 4; ++j)
      b[j] = *reinterpret_cast<const bf16x8*>(&Bs[(wn * 64 + j * 16 + lc) * 32 + lg * 8]);
#pragma unroll
    for (int i = 0; i < 4; ++i)
#pragma unroll
      for (int j = 0; j < 4; ++j)
        acc[i][j] = __builtin_amdgcn_mfma_f32_16x16x32_bf16(a[i], b[j], acc[i][j], 0, 0, 0);
    __syncthreads();
  }

#pragma unroll
  for (int i = 0; i < 4; ++i) {
    const int mg = m0 + wm * 64 + i * 16 + lg * 4;
    const int bb = mg >> 11, t = mg & 2047;
#pragma unroll
    for (int j = 0; j < 4; ++j) {
      const int nl = n0 + wn * 64 + j * 16 + lc;
      const int h = nl >> 6, d = nl & 63;
      const int bh = bb * NH + h;
      const f32x4 v = acc[i][j];
      if (which == 0) {
        bf16* p = Qb + ((size_t)bh * TT + t) * HD + d;
#pragma unroll
        for (int r = 0; r < 4; ++r) p[r * HD] = (bf16)(v[r] * QSCALE);
      } else if (which == 1) {
        bf16* p = Kb + ((size_t)bh * TT + t) * HD + d;
#pragma unroll
        for (int r = 0; r < 4; ++r) p[r * HD] = (bf16)v[r];
      } else {
        bf16x4 pk = { (bf16)v[0], (bf16)v[1], (bf16)v[2], (bf16)v[3] };
        *reinterpret_cast<bf16x4*>(Vtb + ((size_t)bh * HD + d) * TT + t) = pk;
      }
    }
  }
}

// ---------------- flash attention: 32x32 MFMA, in-register P ----------------
// 1024 blocks x 2 waves x 32 q-rows. Static heavy-first mapping + HW backfill
// (1024 blocks > 5x256 slots... 5 blocks/CU resident, 10 waves/CU). XCD-grouped
// bh keeps each XCD's K/V/Q working set in its 4MB L2. Double-buffered LDS
// (32KB/block -> 5 blocks/CU), counted vmcnt(8/0). Swapped QK^T 32x32x16,
// in-register P via cvt_pk+permlane32_swap (T12), defer-max (T13).
#define MF32(a, b, c) __builtin_amdgcn_mfma_f32_32x32x16_bf16((a), (b), (c), 0, 0, 0)

__launch_bounds__(128, 2)
__global__ void attn_fwd(const bf16* __restrict__ Qb, const bf16* __restrict__ Kb,
                         const bf16* __restrict__ Vtb, bf16* __restrict__ Yb) {
  __shared__ bf16 Ks[2][4096];     // 2 x [64 kv x 64 d] swizzled rows (16 KB)
  __shared__ bf16 Vs[2][4096];     // 2 x [64 d x 64 kv] swizzled rows (16 KB)

  const int tid  = threadIdx.x;
  const int lane = tid & 63;
  const int wv   = tid >> 6;         // 0..1
  const int m31  = lane & 31;
  const int hi   = lane >> 5;
  const int hi16 = hi << 4;
  const int hi4  = hi << 2;
  const int xr   = (m31 & 7) << 4;
  const int kRow = m31 * 128;
  int colx[4];
#pragma unroll
  for (int i = 0; i < 4; ++i) colx[i] = (i * 32 + hi16) ^ xr;

  // static chunk mapping: heavy-first qc, XCD-grouped bh
  const int u    = blockIdx.x & 31;
  const int bh   = ((u & 7) << 2) | (u >> 3);
  const int qc   = 31 - (blockIdx.x >> 5);
  const int NT   = qc + 1;
  const int qb0  = qc * 64 + wv * 32;
  const int qrow = qb0 + m31;

  const bf16* Qg = Qb  + (size_t)bh * TT * HD;
  const bf16* Kg = Kb  + (size_t)bh * TT * HD;
  const bf16* Vg = Vtb + (size_t)bh * HD * TT;

  // staging offsets: dest linear (wave-uniform base + lane*16), src pre-swizzled
  int dstb[4], koff[4], voff[4];
#pragma unroll
  for (int c = 0; c < 4; ++c) {
    const int base = (wv * 4 + c) * 1024;
    const int lin  = base + lane * 16;
    dstb[c] = base;
    koff[c] = swzb(lin);
    voff[c] = (lin >> 7) * (TT * 2) + (swzb(lin) & 127);
  }

  // Q fragments (B-operand): lane holds q=m31, d = ds*16 + 8*hi + j
  bf16x8 qr0 = *reinterpret_cast<const bf16x8*>(Qg + (size_t)qrow * HD + 0  + hi * 8);
  bf16x8 qr1 = *reinterpret_cast<const bf16x8*>(Qg + (size_t)qrow * HD + 16 + hi * 8);
  bf16x8 qr2 = *reinterpret_cast<const bf16x8*>(Qg + (size_t)qrow * HD + 32 + hi * 8);
  bf16x8 qr3 = *reinterpret_cast<const bf16x8*>(Qg + (size_t)qrow * HD + 48 + hi * 8);

  f32x16 o0 = {}, o1 = {};           // O^T rows d = dsub*32 + crow, col q = m31
  float m_run = -INFINITY, l_run = 0.f;

#define STAGE(buf, kv)                                                          \
  {                                                                             \
    _Pragma("unroll")                                                           \
    for (int c = 0; c < 4; ++c) {                                               \
      gload_lds16((const bf16*)((const char*)Kg + (size_t)(kv) * 8192 + koff[c]), \
                  (bf16*)((char*)Ks[buf] + dstb[c]));                           \
      gload_lds16((const bf16*)((const char*)Vg + (size_t)(kv) * 128 + voff[c]),  \
                  (bf16*)((char*)Vs[buf] + dstb[c]));                           \
    }                                                                           \
  }

  STAGE(0, 0);                       // 8 per-wave loads outstanding

  int cur = 0;
  for (int ti = 0; ti < NT; ++ti) {
    if (ti + 1 < NT) {
      STAGE(cur ^ 1, ti + 1);
      asm volatile("s_waitcnt vmcnt(8)" ::: "memory");    // tile ti landed
    } else {
      asm volatile("s_waitcnt vmcnt(0)" ::: "memory");
    }
    __builtin_amdgcn_s_barrier();
    __builtin_amdgcn_sched_barrier(0);

    const char* ksb = (const char*)Ks[cur];
    const char* vsb = (const char*)Vs[cur];
    const int k0 = ti * 64;

    // ---- QK^T: S^T[kv][q], A = K (m=kv), B = Q (n=q) ----
    f32x16 s0 = {}, s1 = {};
    __builtin_amdgcn_s_setprio(1);
    {
      bf16x8 kf;
      kf = *reinterpret_cast<const bf16x8*>(ksb + kRow + colx[0]); s0 = MF32(kf, qr0, s0);
      kf = *reinterpret_cast<const bf16x8*>(ksb + kRow + colx[1]); s0 = MF32(kf, qr1, s0);
      kf = *reinterpret_cast<const bf16x8*>(ksb + kRow + colx[2]); s0 = MF32(kf, qr2, s0);
      kf = *reinterpret_cast<const bf16x8*>(ksb + kRow + colx[3]); s0 = MF32(kf, qr3, s0);
      kf = *reinterpret_cast<const bf16x8*>(ksb + 4096 + kRow + colx[0]); s1 = MF32(kf, qr0, s1);
      kf = *reinterpret_cast<const bf16x8*>(ksb + 4096 + kRow + colx[1]); s1 = MF32(kf, qr1, s1);
      kf = *reinterpret_cast<const bf16x8*>(ksb + 4096 + kRow + colx[2]); s1 = MF32(kf, qr2, s1);
      kf = *reinterpret_cast<const bf16x8*>(ksb + 4096 + kRow + colx[3]); s1 = MF32(kf, qr3, s1);
    }
    __builtin_amdgcn_s_setprio(0);

    // ---- causal mask (diagonal tile only) ----
    if (k0 + 63 > qb0) {
#pragma unroll
      for (int r = 0; r < 16; ++r) {
        const int kvl = (r & 3) + 8 * (r >> 2) + hi4;
        if (k0 + kvl > qrow)      s0[r] = -INFINITY;
        if (k0 + 32 + kvl > qrow) s1[r] = -INFINITY;
      }
    }

    // ---- row max: in-lane tree + one cross-half exchange ----
    float q0m = fmaxf(fmaxf(s0[0], s0[1]),  fmaxf(s0[2], s0[3]));
    float q1m = fmaxf(fmaxf(s0[4], s0[5]),  fmaxf(s0[6], s0[7]));
    float q2m = fmaxf(fmaxf(s0[8], s0[9]),  fmaxf(s0[10], s0[11]));
    float q3m = fmaxf(fmaxf(s0[12], s0[13]), fmaxf(s0[14], s0[15]));
    float q4m = fmaxf(fmaxf(s1[0], s1[1]),  fmaxf(s1[2], s1[3]));
    float q5m = fmaxf(fmaxf(s1[4], s1[5]),  fmaxf(s1[6], s1[7]));
    float q6m = fmaxf(fmaxf(s1[8], s1[9]),  fmaxf(s1[10], s1[11]));
    float q7m = fmaxf(fmaxf(s1[12], s1[13]), fmaxf(s1[14], s1[15]));
    float pm = fmaxf(fmaxf(fmaxf(q0m, q1m), fmaxf(q2m, q3m)),
                     fmaxf(fmaxf(q4m, q5m), fmaxf(q6m, q7m)));
    pm = fmaxf(pm, __shfl_xor(pm, 32));

    // ---- T13 defer-rescale ----
    const int need = pm > m_run + 8.f;
    if (__any(need)) {
      const float mn = fmaxf(m_run, pm);
      const float al = __builtin_amdgcn_exp2f(m_run - mn);
      m_run = mn; l_run *= al;
#pragma unroll
      for (int r = 0; r < 16; ++r) { o0[r] *= al; o1[r] *= al; }
    }

#pragma unroll
    for (int r = 0; r < 16; ++r) {
      s0[r] = __builtin_amdgcn_exp2f(s0[r] - m_run);
      s1[r] = __builtin_amdgcn_exp2f(s1[r] - m_run);
    }

    // ---- P -> PV B-fragments in registers (cvt_pk + permlane32_swap) ----
    union PU { u32 w[4]; bf16x8 v; } pu0, pu1, pu2, pu3;
    {
      u32 a0 = cvtpk(s0[0],  s0[1]),  a1 = cvtpk(s0[2],  s0[3]);
      u32 b0 = cvtpk(s0[4],  s0[5]),  b1 = cvtpk(s0[6],  s0[7]);
      plswap(a0, b0); plswap(a1, b1);
      pu0.w[0] = a0; pu0.w[1] = a1; pu0.w[2] = b0; pu0.w[3] = b1;
      u32 c0 = cvtpk(s0[8],  s0[9]),  c1 = cvtpk(s0[10], s0[11]);
      u32 d0 = cvtpk(s0[12], s0[13]), d1 = cvtpk(s0[14], s0[15]);
      plswap(c0, d0); plswap(c1, d1);
      pu1.w[0] = c0; pu1.w[1] = c1; pu1.w[2] = d0; pu1.w[3] = d1;
      u32 e0 = cvtpk(s1[0],  s1[1]),  e1 = cvtpk(s1[2],  s1[3]);
      u32 f0 = cvtpk(s1[4],  s1[5]),  f1 = cvtpk(s1[6],  s1[7]);
      plswap(e0, f0); plswap(e1, f1);
      pu2.w[0] = e0; pu2.w[1] = e1; pu2.w[2] = f0; pu2.w[3] = f1;
      u32 g0 = cvtpk(s1[8],  s1[9]),  g1 = cvtpk(s1[10], s1[11]);
      u32 h0 = cvtpk(s1[12], s1[13]), h1 = cvtpk(s1[14], s1[15]);
      plswap(g0, h0); plswap(g1, h1);
      pu3.w[0] = g0; pu3.w[1] = g1; pu3.w[2] = h0; pu3.w[3] = h1;
    }

    // ---- O^T += V^T P : A = V^T (m=d), B = P (n=q) ----
    __builtin_amdgcn_s_setprio(1);
    {
      bf16x8 vf;
      vf = *reinterpret_cast<const bf16x8*>(vsb + kRow + colx[0]);        o0 = MF32(vf, pu0.v, o0);
      vf = *reinterpret_cast<const bf16x8*>(vsb + 4096 + kRow + colx[0]); o1 = MF32(vf, pu0.v, o1);
      vf = *reinterpret_cast<const bf16x8*>(vsb + kRow + colx[1]);        o0 = MF32(vf, pu1.v, o0);
      vf = *reinterpret_cast<const bf16x8*>(vsb + 4096 + kRow + colx[1]); o1 = MF32(vf, pu1.v, o1);
      vf = *reinterpret_cast<const bf16x8*>(vsb + kRow + colx[2]);        o0 = MF32(vf, pu2.v, o0);
      vf = *reinterpret_cast<const bf16x8*>(vsb + 4096 + kRow + colx[2]); o1 = MF32(vf, pu2.v, o1);
      vf = *reinterpret_cast<const bf16x8*>(vsb + kRow + colx[3]);        o0 = MF32(vf, pu3.v, o0);
      vf = *reinterpret_cast<const bf16x8*>(vsb + 4096 + kRow + colx[3]); o1 = MF32(vf, pu3.v, o1);
    }
    __builtin_amdgcn_s_setprio(0);

    // ---- l-sum (off the pre-PV chain) ----
    float u0 = (s0[0] + s0[1]) + (s0[2] + s0[3]);
    float u1 = (s0[4] + s0[5]) + (s0[6] + s0[7]);
    float u2 = (s0[8] + s0[9]) + (s0[10] + s0[11]);
    float u3 = (s0[12] + s0[13]) + (s0[14] + s0[15]);
    float u4 = (s1[0] + s1[1]) + (s1[2] + s1[3]);
    float u5 = (s1[4] + s1[5]) + (s1[6] + s1[7]);
    float u6 = (s1[8] + s1[9]) + (s1[10] + s1[11]);
    float u7 = (s1[12] + s1[13]) + (s1[14] + s1[15]);
    float rsum = ((u0 + u1) + (u2 + u3)) + ((u4 + u5) + (u6 + u7));
    rsum += __shfl_xor(rsum, 32);
    l_run += rsum;

    __builtin_amdgcn_s_barrier();    // all waves done reading buffer `cur`
    cur ^= 1;
  }
#undef STAGE

  // ---- writeback: y[b*T + q][h*64 + d] ----
  {
    const float linv = 1.f / fmaxf(l_run, 1e-9f);
    bf16* yrow = Yb + ((size_t)((bh >> 4) * TT + qrow)) * DM + (bh & 15) * HD;
#pragma unroll
    for (int rq = 0; rq < 4; ++rq) {
      bf16x4 y0 = { (bf16)(o0[rq * 4 + 0] * linv), (bf16)(o0[rq * 4 + 1] * linv),
                    (bf16)(o0[rq * 4 + 2] * linv), (bf16)(o0[rq * 4 + 3] * linv) };
      *reinterpret_cast<bf16x4*>(yrow + rq * 8 + hi4) = y0;
      bf16x4 y1 = { (bf16)(o1[rq * 4 + 0] * linv), (bf16)(o1[rq * 4 + 1] * linv),
                    (bf16)(o1[rq * 4 + 2] * linv), (bf16)(o1[rq * 4 + 3] * linv) };
      *reinterpret_cast<bf16x4*>(yrow + 32 + rq * 8 + hi4) = y1;
    }
  }
}

// ---------------- output projection (64x128 tiles, 512 blocks = 2/CU) -------
__launch_bounds__(256, 2)
__global__ void gemm_out(const bf16* __restrict__ Y, const bf16* __restrict__ Wo,
                         float* __restrict__ Out) {
  __shared__ bf16 As[64 * 32];
  __shared__ bf16 Bs[128 * 32];
  const int tid  = threadIdx.x;
  const int lane = tid & 63;
  const int wv   = tid >> 6;
  const int lg   = lane >> 4, lc = lane & 15;
  const int m0   = blockIdx.x * 64;
  const int n0   = blockIdx.y * 128;
  const int wm = wv >> 1, wn = wv & 1;   // wave tile: 32 rows x 64 cols

  f32x4 acc[2][4] = {};

  for (int k0 = 0; k0 < DM; k0 += 32) {
    {
      const int e   = wv * 512 + lane * 8;
      const int row = e >> 5, col = e & 31;
      gload_lds16(Y + (size_t)(m0 + row) * DM + k0 + col, &As[wv * 512]);
    }
#pragma unroll
    for (int c = 0; c < 2; ++c) {
      const int e   = wv * 1024 + c * 512 + lane * 8;
      const int row = e >> 5, col = e & 31;
      gload_lds16(Wo + (size_t)(n0 + row) * DM + k0 + col, &Bs[wv * 1024 + c * 512]);
    }
    __syncthreads();
    bf16x8 a[2], b[4];
#pragma unroll
    for (int i = 0; i < 2; ++i)
      a[i] = *reinterpret_cast<const bf16x8*>(&As[(wm * 32 + i * 16 + lc) * 32 + lg * 8]);
#pragma unroll
    for (int j = 0; j < 4; ++j)
      b[j] = *reinterpret_cast<const bf16x8*>(&Bs[(wn * 64 + j * 16 + lc) * 32 + lg * 8]);
#pragma unroll
    for (int i = 0; i < 2; ++i)
#pragma unroll
      for (int j = 0; j < 4; ++j)
        acc[i][j] = __builtin_amdgcn_mfma_f32_16x16x32_bf16(a[i], b[j], acc[i][j], 0, 0, 0);
    __syncthreads();
  }

#pragma unroll
  for (int i = 0; i < 2; ++i) {
    const int mg = m0 + wm * 32 + i * 16 + lg * 4;
#pragma unroll
    for (int j = 0; j < 4; ++j) {
      const int n = n0 + wn * 64 + j * 16 + lc;
#pragma unroll
      for (int r = 0; r < 4; ++r)
        Out[(size_t)(mg + r) * DM + n] = acc[i][j][r];
    }
  }
}

extern "C" void kernel_launch(void* const* d_in, const int* in_sizes, int n_in,
                              void* d_out, int out_size, void* d_ws, size_t ws_size,
                              hipStream_t stream) {
  const float* x  = (const float*)d_in[0];
  const float* Wq = (const float*)d_in[1];
  const float* Wk = (const float*)d_in[2];
  const float* Wv = (const float*)d_in[3];
  const float* Wo = (const float*)d_in[4];
  float* out = (float*)d_out;
  char* ws = (char*)d_ws;
  const size_t MB = 1024 * 1024;

  bf16* xb  = (bf16*)(ws + 0);        // 8 MB, reused as yb after QKV GEMM
  bf16* wqb = (bf16*)(ws + 8  * MB);
  bf16* wkb = (bf16*)(ws + 10 * MB);
  bf16* wvb = (bf16*)(ws + 12 * MB);
  bf16* wob = (bf16*)(ws + 14 * MB);
  bf16* Qb  = (bf16*)(ws + 16 * MB);  // [32,2048,64]
  bf16* Kb  = (bf16*)(ws + 24 * MB);
  bf16* Vtb = (bf16*)(ws + 32 * MB);  // [32,64,2048]
  bf16* yb  = xb;

  cvt_all<<<8192, 256, 0, stream>>>(x, Wq, Wk, Wv, Wo, xb, wqb, wkb, wvb, wob);
  gemm_qkv<<<dim3(32, 24), 256, 0, stream>>>(xb, wqb, wkb, wvb, Qb, Kb, Vtb);
  attn_fwd<<<1024, 128, 0, stream>>>(Qb, Kb, Vtb, yb);
  gemm_out<<<dim3(64, 8), 256, 0, stream>>>(yb, wob, out);
}